// Round 4
// baseline (203.768 us; speedup 1.0000x reference)
//
#include <hip/hip_runtime.h>

// MoreParamDenseQConv1D: quantum-circuit conv1d.
// B=16, C_in=4, L=2048, K=8, OUT_CH=8, N_LAYERS=2, N_QUBITS=7, DIM=128.
// One wave evolves NS=4 independent (row, oc) 128-dim complex states
// (2 complex amps per lane per state). The acting qubit is kept in the
// "slot" axis via slot<->lane-bit re-pairings:
//   m=32 -> v_permlane32_swap_b32   (1 VALU instr per register)
//   m=16 -> v_permlane16_swap_b32
//   m=8,4 -> ds_bpermute + cndmask  (only 4 LDS-pipe repairs per state)
//   m=2,1 -> DPP quad_perm + cndmask (pure VALU)
// Normalization is deferred: evolve the raw window (linear), divide the
// measured expectation by sum(x^2) at the end. Final reductions use the
// classic gfx9 DPP row_shr/row_bcast sequence (result in lane 63).
// Gates are computed per-wave (lanes 0-13) and broadcast to SGPRs via
// v_readlane — single kernel, no prep launch, no graph edge.

#define L_OUT 2041
#define N_ROWS (16 * L_OUT)   // 32656
#define NS 4
#define N_BLK (N_ROWS / NS)   // 8164 blocks x 8 waves

__device__ __forceinline__ float bperm(int addr, float v) {
    return __int_as_float(__builtin_amdgcn_ds_bpermute(addr, __float_as_int(v)));
}

template <int CTRL>
__device__ __forceinline__ float fdpp(float v) {
    return __int_as_float(
        __builtin_amdgcn_mov_dpp(__float_as_int(v), CTRL, 0xf, 0xf, true));
}

// Full-wave sum; total lands in lane 63. Zero LDS ops.
__device__ __forceinline__ float dpp_reduce(float v) {
    v += fdpp<0x111>(v);  // row_shr:1
    v += fdpp<0x112>(v);  // row_shr:2
    v += fdpp<0x114>(v);  // row_shr:4
    v += fdpp<0x118>(v);  // row_shr:8
    v += fdpp<0x142>(v);  // row_bcast:15
    v += fdpp<0x143>(v);  // row_bcast:31
    return v;
}

__global__ __launch_bounds__(512) void qconv_k(const float* __restrict__ x,
                                               const float* __restrict__ thetas,
                                               float* __restrict__ out) {
    int lane = threadIdx.x & 63;
    int oc = __builtin_amdgcn_readfirstlane(threadIdx.x >> 6);  // 0..7

    // ---- row indices + window loads (issue early) ----
    int row0 = blockIdx.x * NS;
    int bidx[NS], lidx[NS];
    float xv[NS];
#pragma unroll
    for (int s = 0; s < NS; ++s) {
        int row = row0 + s;
        int b = row / L_OUT;
        bidx[s] = b;
        lidx[s] = row - b * L_OUT;
        float t = 0.f;
        if (lane < 32) {
            int c = lane >> 3, k = lane & 7;
            t = x[(b * 4 + c) * 2048 + lidx[s] + k];
        }
        xv[s] = t;
    }

    // ---- per-wave gate computation: lanes 0..13 each build one gate ----
    // gate g = l*7 + q for this wave's oc; store u00r,u00i,u10r,u10i.
    float o0, o1, o2, o3;
    {
        int g = lane < 14 ? lane : 0;
        int ti = (oc * 14 + g) * 3;
        float a = thetas[ti + 0], b = thetas[ti + 1], gm = thetas[ti + 2];
        float sb = __sinf(b * 0.5f), cb = __cosf(b * 0.5f);
        float sp, cp, sm, cm;
        __sincosf((a + gm) * 0.5f, &sp, &cp);
        __sincosf((a - gm) * 0.5f, &sm, &cm);
        o0 = cp * cb;
        o1 = -sp * cb;
        o2 = cm * sb;
        o3 = sm * sb;
    }
    // broadcast to wave-uniform (SGPR) values
    float gc[56];
#pragma unroll
    for (int k = 0; k < 14; ++k) {
        gc[k * 4 + 0] = __int_as_float(__builtin_amdgcn_readlane(__float_as_int(o0), k));
        gc[k * 4 + 1] = __int_as_float(__builtin_amdgcn_readlane(__float_as_int(o1), k));
        gc[k * 4 + 2] = __int_as_float(__builtin_amdgcn_readlane(__float_as_int(o2), k));
        gc[k * 4 + 3] = __int_as_float(__builtin_amdgcn_readlane(__float_as_int(o3), k));
    }

    // ---- init: raw (unnormalized) state; carry acc = sum(x^2) ----
    float acc[NS];
    float v0r[NS], v0i[NS], v1r[NS], v1i[NS];
#pragma unroll
    for (int s = 0; s < NS; ++s) {
        acc[s] = xv[s] * xv[s];
        v0r[s] = xv[s]; v0i[s] = 0.f; v1r[s] = 0.f; v1i[s] = 0.f;
    }

#define GAPPLY(gi)                                                        \
    {                                                                     \
        float ur = gc[(gi)*4 + 0], ui = gc[(gi)*4 + 1];                   \
        float vr = gc[(gi)*4 + 2], vi = gc[(gi)*4 + 3];                   \
        _Pragma("unroll") for (int s = 0; s < NS; ++s) {                  \
            float n0r = ur * v0r[s] - ui * v0i[s] - vr * v1r[s] - vi * v1i[s]; \
            float n0i = ur * v0i[s] + ui * v0r[s] + vi * v1r[s] - vr * v1i[s]; \
            float n1r = vr * v0r[s] - vi * v0i[s] + ur * v1r[s] + ui * v1i[s]; \
            float n1i = vr * v0i[s] + vi * v0r[s] + ur * v1i[s] - ui * v1r[s]; \
            v0r[s] = n0r; v0i[s] = n0i; v1r[s] = n1r; v1i[s] = n1i;       \
        }                                                                 \
    }

// slot <-> lane-bit 5: swap v0.hi-half with v1.lo-half
#define RP32()                                                            \
    {                                                                     \
        _Pragma("unroll") for (int s = 0; s < NS; ++s) {                  \
            asm("v_permlane32_swap_b32 %0, %1" : "+v"(v0r[s]), "+v"(v1r[s])); \
            asm("v_permlane32_swap_b32 %0, %1" : "+v"(v0i[s]), "+v"(v1i[s])); \
        }                                                                 \
    }

// slot <-> lane-bit 4
#define RP16()                                                            \
    {                                                                     \
        _Pragma("unroll") for (int s = 0; s < NS; ++s) {                  \
            asm("v_permlane16_swap_b32 %0, %1" : "+v"(v0r[s]), "+v"(v1r[s])); \
            asm("v_permlane16_swap_b32 %0, %1" : "+v"(v0i[s]), "+v"(v1i[s])); \
        }                                                                 \
    }

// slot <-> lane-bit via ds_bpermute (m = 8, 4)
#define RPB(m)                                                            \
    {                                                                     \
        bool hi = (lane & (m)) != 0;                                      \
        int ad = (lane ^ (m)) << 2;                                       \
        _Pragma("unroll") for (int s = 0; s < NS; ++s) {                  \
            float sr = hi ? v0r[s] : v1r[s];                              \
            float si = hi ? v0i[s] : v1i[s];                              \
            float rr = bperm(ad, sr);                                     \
            float ri = bperm(ad, si);                                     \
            v0r[s] = hi ? rr : v0r[s];                                    \
            v0i[s] = hi ? ri : v0i[s];                                    \
            v1r[s] = hi ? v1r[s] : rr;                                    \
            v1i[s] = hi ? v1i[s] : ri;                                    \
        }                                                                 \
    }

// slot <-> lane-bit via DPP quad_perm (m = 2 -> 0x4E, m = 1 -> 0xB1); pure VALU
#define RPD(m, CTRL)                                                      \
    {                                                                     \
        bool hi = (lane & (m)) != 0;                                      \
        _Pragma("unroll") for (int s = 0; s < NS; ++s) {                  \
            float t0r = fdpp<CTRL>(v0r[s]), t0i = fdpp<CTRL>(v0i[s]);     \
            float t1r = fdpp<CTRL>(v1r[s]), t1i = fdpp<CTRL>(v1i[s]);     \
            v0r[s] = hi ? t1r : v0r[s];                                   \
            v0i[s] = hi ? t1i : v0i[s];                                   \
            v1r[s] = hi ? v1r[s] : t0r;                                   \
            v1i[s] = hi ? v1i[s] : t0i;                                   \
        }                                                                 \
    }

    // ---- layer 1 ----
    // gate q=0 (amp bit 6 in slot): a1 = 0, a0 real
    {
        float ur = gc[0], ui = gc[1], vr = gc[2], vi = gc[3];
#pragma unroll
        for (int s = 0; s < NS; ++s) {
            float xx = v0r[s];
            v0r[s] = ur * xx; v0i[s] = ui * xx;
            v1r[s] = vr * xx; v1i[s] = vi * xx;
        }
    }
    RP32();
    // gate q=1: slot = amp bit 5; slot-1 amps still all zero
    {
        float ur = gc[4], ui = gc[5], vr = gc[6], vi = gc[7];
#pragma unroll
        for (int s = 0; s < NS; ++s) {
            float x0r = v0r[s], x0i = v0i[s];
            v0r[s] = ur * x0r - ui * x0i; v0i[s] = ur * x0i + ui * x0r;
            v1r[s] = vr * x0r - vi * x0i; v1i[s] = vr * x0i + vi * x0r;
        }
    }
    RP16();       GAPPLY(2);
    RPB(8);       GAPPLY(3);
    RPB(4);       GAPPLY(4);
    RPD(2, 0x4E); GAPPLY(5);
    RPD(1, 0xB1); GAPPLY(6);

    // entangle diag: sign(popcount) — invariant under the bit permutation
    int kc = __popc(lane);
    float s0 = ((kc >> 1) & 1) ? -1.f : 1.f;
    float s1 = (((kc + 1) >> 1) & 1) ? -1.f : 1.f;
#pragma unroll
    for (int s = 0; s < NS; ++s) {
        v0r[s] *= s0; v0i[s] *= s0; v1r[s] *= s1; v1i[s] *= s1;
    }

    // ---- layer 2 ----
    RP32();       GAPPLY(7);    // amp6
    RP16();       GAPPLY(8);    // amp5
    RPB(8);       GAPPLY(9);    // amp4
    RPB(4);       GAPPLY(10);   // amp3
    RPD(2, 0x4E); GAPPLY(11);   // amp2
    RPD(1, 0xB1); GAPPLY(12);   // amp1
    RP32();       GAPPLY(13);   // amp0
#pragma unroll
    for (int s = 0; s < NS; ++s) {
        v0r[s] *= s0; v0i[s] *= s0; v1r[s] *= s1; v1i[s] *= s1;
    }

    // measurement: z0 sign = -1 iff amp bit6 == 1; amp bit6 now on lane bit 4
    float e[NS];
#pragma unroll
    for (int s = 0; s < NS; ++s) {
        float t = v0r[s] * v0r[s] + v0i[s] * v0i[s] + v1r[s] * v1r[s] + v1i[s] * v1i[s];
        e[s] = (lane & 16) ? -t : t;
    }
#pragma unroll
    for (int s = 0; s < NS; ++s) {
        e[s] = dpp_reduce(e[s]);      // lane 63 = sum
        acc[s] = dpp_reduce(acc[s]);  // lane 63 = sum(x^2)
    }
    if (lane == 63) {
#pragma unroll
        for (int s = 0; s < NS; ++s)
            out[(bidx[s] * 8 + oc) * L_OUT + lidx[s]] =
                e[s] * __builtin_amdgcn_rcpf(acc[s]);
    }
#undef GAPPLY
#undef RP32
#undef RP16
#undef RPB
#undef RPD
}

extern "C" void kernel_launch(void* const* d_in, const int* in_sizes, int n_in,
                              void* d_out, int out_size, void* d_ws, size_t ws_size,
                              hipStream_t stream) {
    const float* x = (const float*)d_in[0];
    const float* thetas = (const float*)d_in[1];
    float* out = (float*)d_out;
    qconv_k<<<N_BLK, 512, 0, stream>>>(x, thetas, out);
}

// Round 5
// 79.594 us; speedup vs baseline: 2.5601x; 2.5601x over previous
//
#include <hip/hip_runtime.h>

// MoreParamDenseQConv1D — algebraic reduction.
// The circuit (2 layers x 7 gates + entangler diag) is x-independent, so the
// whole evolution is a fixed linear map W per out-channel. psi0 is real with
// only 32 nonzero entries (the normalized window w), hence
//   out(r,oc) = w^T A_oc w / (w^T w),  A_oc = Re(W[:,:32]^H diag(z0) W[:,:32])
// a real symmetric 32x32 matrix. Pipeline:
//   1) prep_k : evolve 528 basis inputs per oc (32 singles e_k, 496 pairs
//      e_k+e_l) with the verified wave-level circuit machinery (unnormalized
//      evolution is exactly linear) -> f values in ws.
//   2) asm_k  : polarization identity A_kl = (f(e_k+e_l) - f_k - f_l)/2.
//   3) quad_k : one thread per (row,oc): 32 window floats in VGPRs, 1056 FMA
//      against wave-uniform A rows (scalar loads), divide by ||w||^2.

#define L_OUT 2041
#define N_ROWS (16 * L_OUT)   // 32656
#define NS 4

// ---------------- wave-level circuit machinery (verified R1-R4) -------------

__device__ __forceinline__ float bperm(int addr, float v) {
    return __int_as_float(__builtin_amdgcn_ds_bpermute(addr, __float_as_int(v)));
}

template <int CTRL>
__device__ __forceinline__ float fdpp(float v) {
    return __int_as_float(
        __builtin_amdgcn_mov_dpp(__float_as_int(v), CTRL, 0xf, 0xf, true));
}

// Full-wave sum; total lands in lane 63.
__device__ __forceinline__ float dpp_reduce(float v) {
    v += fdpp<0x111>(v);  // row_shr:1
    v += fdpp<0x112>(v);  // row_shr:2
    v += fdpp<0x114>(v);  // row_shr:4
    v += fdpp<0x118>(v);  // row_shr:8
    v += fdpp<0x142>(v);  // row_bcast:15
    v += fdpp<0x143>(v);  // row_bcast:31
    return v;
}

// Per-wave gate table for one oc: lanes 0..13 each build one gate
// (u00r,u00i,u10r,u10i), broadcast to wave-uniform gc[56] via readlane.
__device__ __forceinline__ void make_gates(const float* __restrict__ thetas,
                                           int oc, int lane, float* gc) {
    float o0, o1, o2, o3;
    {
        int g = lane < 14 ? lane : 0;
        int ti = (oc * 14 + g) * 3;
        float a = thetas[ti + 0], b = thetas[ti + 1], gm = thetas[ti + 2];
        float sb = sinf(b * 0.5f), cb = cosf(b * 0.5f);
        float sp, cp, sm, cm;
        sincosf((a + gm) * 0.5f, &sp, &cp);
        sincosf((a - gm) * 0.5f, &sm, &cm);
        o0 = cp * cb;
        o1 = -sp * cb;
        o2 = cm * sb;
        o3 = sm * sb;
    }
#pragma unroll
    for (int k = 0; k < 14; ++k) {
        gc[k * 4 + 0] = __int_as_float(__builtin_amdgcn_readlane(__float_as_int(o0), k));
        gc[k * 4 + 1] = __int_as_float(__builtin_amdgcn_readlane(__float_as_int(o1), k));
        gc[k * 4 + 2] = __int_as_float(__builtin_amdgcn_readlane(__float_as_int(o2), k));
        gc[k * 4 + 3] = __int_as_float(__builtin_amdgcn_readlane(__float_as_int(o3), k));
    }
}

// Evolve NS states through the full circuit (both layers + both entangler
// diags). Input: v0r real, v0i=v1r=v1i=0, amps 32..127 zero. Unnormalized.
__device__ __forceinline__ void evolve(float (&v0r)[NS], float (&v0i)[NS],
                                       float (&v1r)[NS], float (&v1i)[NS],
                                       const float (&gc)[56], int lane) {
#define GAPPLY(gi)                                                        \
    {                                                                     \
        float ur = gc[(gi)*4 + 0], ui = gc[(gi)*4 + 1];                   \
        float vr = gc[(gi)*4 + 2], vi = gc[(gi)*4 + 3];                   \
        _Pragma("unroll") for (int s = 0; s < NS; ++s) {                  \
            float n0r = ur * v0r[s] - ui * v0i[s] - vr * v1r[s] - vi * v1i[s]; \
            float n0i = ur * v0i[s] + ui * v0r[s] + vi * v1r[s] - vr * v1i[s]; \
            float n1r = vr * v0r[s] - vi * v0i[s] + ur * v1r[s] + ui * v1i[s]; \
            float n1i = vr * v0i[s] + vi * v0r[s] + ur * v1i[s] - ui * v1r[s]; \
            v0r[s] = n0r; v0i[s] = n0i; v1r[s] = n1r; v1i[s] = n1i;       \
        }                                                                 \
    }
#define RP32()                                                            \
    {                                                                     \
        _Pragma("unroll") for (int s = 0; s < NS; ++s) {                  \
            asm("v_permlane32_swap_b32 %0, %1" : "+v"(v0r[s]), "+v"(v1r[s])); \
            asm("v_permlane32_swap_b32 %0, %1" : "+v"(v0i[s]), "+v"(v1i[s])); \
        }                                                                 \
    }
#define RP16()                                                            \
    {                                                                     \
        _Pragma("unroll") for (int s = 0; s < NS; ++s) {                  \
            asm("v_permlane16_swap_b32 %0, %1" : "+v"(v0r[s]), "+v"(v1r[s])); \
            asm("v_permlane16_swap_b32 %0, %1" : "+v"(v0i[s]), "+v"(v1i[s])); \
        }                                                                 \
    }
#define RPB(m)                                                            \
    {                                                                     \
        bool hi = (lane & (m)) != 0;                                      \
        int ad = (lane ^ (m)) << 2;                                       \
        _Pragma("unroll") for (int s = 0; s < NS; ++s) {                  \
            float sr = hi ? v0r[s] : v1r[s];                              \
            float si = hi ? v0i[s] : v1i[s];                              \
            float rr = bperm(ad, sr);                                     \
            float ri = bperm(ad, si);                                     \
            v0r[s] = hi ? rr : v0r[s];                                    \
            v0i[s] = hi ? ri : v0i[s];                                    \
            v1r[s] = hi ? v1r[s] : rr;                                    \
            v1i[s] = hi ? v1i[s] : ri;                                    \
        }                                                                 \
    }
#define RPD(m, CTRL)                                                      \
    {                                                                     \
        bool hi = (lane & (m)) != 0;                                      \
        _Pragma("unroll") for (int s = 0; s < NS; ++s) {                  \
            float t0r = fdpp<CTRL>(v0r[s]), t0i = fdpp<CTRL>(v0i[s]);     \
            float t1r = fdpp<CTRL>(v1r[s]), t1i = fdpp<CTRL>(v1i[s]);     \
            v0r[s] = hi ? t1r : v0r[s];                                   \
            v0i[s] = hi ? t1i : v0i[s];                                   \
            v1r[s] = hi ? v1r[s] : t0r;                                   \
            v1i[s] = hi ? v1i[s] : t0i;                                   \
        }                                                                 \
    }
    // layer 1: gate q=0 special (a1=0, a0 real)
    {
        float ur = gc[0], ui = gc[1], vr = gc[2], vi = gc[3];
#pragma unroll
        for (int s = 0; s < NS; ++s) {
            float xx = v0r[s];
            v0r[s] = ur * xx; v0i[s] = ui * xx;
            v1r[s] = vr * xx; v1i[s] = vi * xx;
        }
    }
    RP32();
    // gate q=1 special (slot-1 amps all zero)
    {
        float ur = gc[4], ui = gc[5], vr = gc[6], vi = gc[7];
#pragma unroll
        for (int s = 0; s < NS; ++s) {
            float x0r = v0r[s], x0i = v0i[s];
            v0r[s] = ur * x0r - ui * x0i; v0i[s] = ur * x0i + ui * x0r;
            v1r[s] = vr * x0r - vi * x0i; v1i[s] = vr * x0i + vi * x0r;
        }
    }
    RP16();       GAPPLY(2);
    RPB(8);       GAPPLY(3);
    RPB(4);       GAPPLY(4);
    RPD(2, 0x4E); GAPPLY(5);
    RPD(1, 0xB1); GAPPLY(6);

    int kc = __popc(lane);
    float s0 = ((kc >> 1) & 1) ? -1.f : 1.f;
    float s1 = (((kc + 1) >> 1) & 1) ? -1.f : 1.f;
#pragma unroll
    for (int s = 0; s < NS; ++s) {
        v0r[s] *= s0; v0i[s] *= s0; v1r[s] *= s1; v1i[s] *= s1;
    }

    // layer 2
    RP32();       GAPPLY(7);
    RP16();       GAPPLY(8);
    RPB(8);       GAPPLY(9);
    RPB(4);       GAPPLY(10);
    RPD(2, 0x4E); GAPPLY(11);
    RPD(1, 0xB1); GAPPLY(12);
    RP32();       GAPPLY(13);
#pragma unroll
    for (int s = 0; s < NS; ++s) {
        v0r[s] *= s0; v0i[s] *= s0; v1r[s] *= s1; v1i[s] *= s1;
    }
#undef GAPPLY
#undef RP32
#undef RP16
#undef RPB
#undef RPD
}

// Measured expectation (z0 weighting: amp bit6 ended on lane bit4): lane 63.
__device__ __forceinline__ void measure(float (&v0r)[NS], float (&v0i)[NS],
                                        float (&v1r)[NS], float (&v1i)[NS],
                                        int lane, float (&e)[NS]) {
#pragma unroll
    for (int s = 0; s < NS; ++s) {
        float t = v0r[s] * v0r[s] + v0i[s] * v0i[s] + v1r[s] * v1r[s] + v1i[s] * v1i[s];
        e[s] = (lane & 16) ? -t : t;
        e[s] = dpp_reduce(e[s]);
    }
}

// ---------------- kernel 1: basis evolutions -> f values --------------------
// grid: 8 oc x 17 chunks = 136 blocks x 512 threads (8 waves x NS=4 inputs).
// input idx in [0,528): idx<32 -> e_idx; else pair p=idx-32 -> e_k+e_l (k<l).
__global__ __launch_bounds__(512) void prep_k(const float* __restrict__ thetas,
                                              float* __restrict__ fbuf) {
    int lane = threadIdx.x & 63;
    int iw = threadIdx.x >> 6;
    int oc = __builtin_amdgcn_readfirstlane(blockIdx.x / 17);
    int chunk = blockIdx.x % 17;

    float gc[56];
    make_gates(thetas, oc, lane, gc);

    float v0r[NS], v0i[NS], v1r[NS], v1i[NS];
    int idxs[NS];
#pragma unroll
    for (int s = 0; s < NS; ++s) {
        int idx = chunk * 32 + iw * 4 + s;
        if (idx > 527) idx = 527;
        idxs[s] = idx;
        int k, l;
        if (idx < 32) {
            k = idx; l = idx;
        } else {
            int p = idx - 32, kk = 0, off = 0;
            while (p >= off + 31 - kk) { off += 31 - kk; ++kk; }
            k = kk;
            l = kk + 1 + (p - off);
        }
        v0r[s] = (lane == k || lane == l) ? 1.f : 0.f;
        v0i[s] = 0.f; v1r[s] = 0.f; v1i[s] = 0.f;
    }

    evolve(v0r, v0i, v1r, v1i, gc, lane);
    float e[NS];
    measure(v0r, v0i, v1r, v1i, lane, e);
    if (lane == 63) {
#pragma unroll
        for (int s = 0; s < NS; ++s) fbuf[oc * 544 + idxs[s]] = e[s];
    }
}

// ---------------- kernel 2: polarization assembly of A ----------------------
__global__ void asm_k(const float* __restrict__ fbuf, float* __restrict__ A) {
    int e = blockIdx.x * 512 + threadIdx.x;  // 16 blocks x 512 = 8192 entries
    if (e >= 8192) return;
    int oc = e >> 10, r = e & 1023, k = r >> 5, l = r & 31;
    const float* fo = fbuf + oc * 544;
    float v;
    if (k == l) {
        v = fo[k];
    } else {
        int kk = k < l ? k : l, ll = k < l ? l : k;
        int off = kk * 31 - (kk * (kk - 1)) / 2;
        v = 0.5f * (fo[32 + off + (ll - kk - 1)] - fo[kk] - fo[ll]);
    }
    A[e] = v;
}

// ---------------- kernel 3: quadratic form over windows ---------------------
// block = 512 threads: lane -> row (64 rows/block), wave -> oc.
__global__ __launch_bounds__(512) void quad_k(const float* __restrict__ x,
                                              const float* __restrict__ A,
                                              float* __restrict__ out) {
    int lane = threadIdx.x & 63;
    int oc = __builtin_amdgcn_readfirstlane((int)(threadIdx.x >> 6));
    int row = blockIdx.x * 64 + lane;
    bool valid = row < N_ROWS;
    int rc = valid ? row : (N_ROWS - 1);
    int b = rc / L_OUT;
    int l = rc - b * L_OUT;

    const float* xb = x + (b * 4) * 2048 + l;
    float w[32];
#pragma unroll
    for (int c = 0; c < 4; ++c)
#pragma unroll
        for (int k = 0; k < 8; ++k) w[c * 8 + k] = xb[c * 2048 + k];

    float n2 = 0.f;
#pragma unroll
    for (int i = 0; i < 32; ++i) n2 = fmaf(w[i], w[i], n2);

    const float* Ao = A + oc * 1024;  // wave-uniform -> scalar loads
    float acc = 0.f;
#pragma unroll 4
    for (int k = 0; k < 32; ++k) {
        const float* Ar = Ao + k * 32;
        float t0 = 0.f, t1 = 0.f;
#pragma unroll
        for (int j = 0; j < 16; ++j) {
            t0 = fmaf(Ar[2 * j + 0], w[2 * j + 0], t0);
            t1 = fmaf(Ar[2 * j + 1], w[2 * j + 1], t1);
        }
        acc = fmaf(w[k], t0 + t1, acc);
    }
    if (valid)
        out[(b * 8 + oc) * L_OUT + l] = acc * __builtin_amdgcn_rcpf(n2);
}

// ---------------- fallback: direct evolution (R4-style) ---------------------
__global__ __launch_bounds__(512) void direct_k(const float* __restrict__ x,
                                                const float* __restrict__ thetas,
                                                float* __restrict__ out) {
    int lane = threadIdx.x & 63;
    int oc = __builtin_amdgcn_readfirstlane((int)(threadIdx.x >> 6));
    float gc[56];
    make_gates(thetas, oc, lane, gc);

    int row0 = blockIdx.x * NS;
    int bidx[NS], lidx[NS];
    float v0r[NS], v0i[NS], v1r[NS], v1i[NS], acc[NS];
#pragma unroll
    for (int s = 0; s < NS; ++s) {
        int row = row0 + s;
        int b = row / L_OUT;
        bidx[s] = b;
        lidx[s] = row - b * L_OUT;
        float t = 0.f;
        if (lane < 32) {
            int c = lane >> 3, k = lane & 7;
            t = x[(b * 4 + c) * 2048 + lidx[s] + k];
        }
        acc[s] = t * t;
        v0r[s] = t; v0i[s] = 0.f; v1r[s] = 0.f; v1i[s] = 0.f;
    }
    evolve(v0r, v0i, v1r, v1i, gc, lane);
    float e[NS];
    measure(v0r, v0i, v1r, v1i, lane, e);
#pragma unroll
    for (int s = 0; s < NS; ++s) acc[s] = dpp_reduce(acc[s]);
    if (lane == 63) {
#pragma unroll
        for (int s = 0; s < NS; ++s)
            out[(bidx[s] * 8 + oc) * L_OUT + lidx[s]] =
                e[s] * __builtin_amdgcn_rcpf(acc[s]);
    }
}

extern "C" void kernel_launch(void* const* d_in, const int* in_sizes, int n_in,
                              void* d_out, int out_size, void* d_ws, size_t ws_size,
                              hipStream_t stream) {
    const float* x = (const float*)d_in[0];
    const float* thetas = (const float*)d_in[1];
    float* out = (float*)d_out;

    // ws: f values 8*544 floats, then A 8*1024 floats = 50176 bytes total.
    if (ws_size >= (8 * 544 + 8 * 1024) * sizeof(float)) {
        float* fbuf = (float*)d_ws;
        float* A = fbuf + 8 * 544;
        prep_k<<<136, 512, 0, stream>>>(thetas, fbuf);
        asm_k<<<16, 512, 0, stream>>>(fbuf, A);
        quad_k<<<(N_ROWS + 63) / 64, 512, 0, stream>>>(x, A, out);
    } else {
        direct_k<<<N_ROWS / NS, 512, 0, stream>>>(x, thetas, out);
    }
}

// Round 6
// 74.285 us; speedup vs baseline: 2.7431x; 1.0715x over previous
//
#include <hip/hip_runtime.h>

// MoreParamDenseQConv1D — algebraic reduction.
// out(r,oc) = w^T A_oc w / (w^T w) with A_oc = Re(W[:,:32]^H diag(z0) W[:,:32])
// (circuit is x-independent; psi0 real, 32 nonzeros). Pipeline:
//   1) prep_k : evolve 528 basis inputs per oc (32 singles e_k, 496 pairs
//      e_k+e_l) with the verified wave-level circuit machinery -> f values.
//   2) asm_k  : triangular U: U_kk = f_k ; U_kl(k<l) = f_pair - f_k - f_l
//      (= 2*A_kl). 528 floats per oc, stored in quad's exact read order.
//   3) quad_k : one thread per (row,oc): 32 window floats in VGPRs,
//      out = sum_{k<=l} U_kl w_k w_l / ||w||^2  (~560 FMA, 528 sequential
//      wave-uniform loads -> wide scalar loads).

#define L_OUT 2041
#define N_ROWS (16 * L_OUT)   // 32656
#define NS 4

// ---------------- wave-level circuit machinery (verified R1-R5) -------------

__device__ __forceinline__ float bperm(int addr, float v) {
    return __int_as_float(__builtin_amdgcn_ds_bpermute(addr, __float_as_int(v)));
}

template <int CTRL>
__device__ __forceinline__ float fdpp(float v) {
    return __int_as_float(
        __builtin_amdgcn_mov_dpp(__float_as_int(v), CTRL, 0xf, 0xf, true));
}

// Full-wave sum; total lands in lane 63.
__device__ __forceinline__ float dpp_reduce(float v) {
    v += fdpp<0x111>(v);  // row_shr:1
    v += fdpp<0x112>(v);  // row_shr:2
    v += fdpp<0x114>(v);  // row_shr:4
    v += fdpp<0x118>(v);  // row_shr:8
    v += fdpp<0x142>(v);  // row_bcast:15
    v += fdpp<0x143>(v);  // row_bcast:31
    return v;
}

__device__ __forceinline__ void make_gates(const float* __restrict__ thetas,
                                           int oc, int lane, float* gc) {
    float o0, o1, o2, o3;
    {
        int g = lane < 14 ? lane : 0;
        int ti = (oc * 14 + g) * 3;
        float a = thetas[ti + 0], b = thetas[ti + 1], gm = thetas[ti + 2];
        float sb = sinf(b * 0.5f), cb = cosf(b * 0.5f);
        float sp, cp, sm, cm;
        sincosf((a + gm) * 0.5f, &sp, &cp);
        sincosf((a - gm) * 0.5f, &sm, &cm);
        o0 = cp * cb;
        o1 = -sp * cb;
        o2 = cm * sb;
        o3 = sm * sb;
    }
#pragma unroll
    for (int k = 0; k < 14; ++k) {
        gc[k * 4 + 0] = __int_as_float(__builtin_amdgcn_readlane(__float_as_int(o0), k));
        gc[k * 4 + 1] = __int_as_float(__builtin_amdgcn_readlane(__float_as_int(o1), k));
        gc[k * 4 + 2] = __int_as_float(__builtin_amdgcn_readlane(__float_as_int(o2), k));
        gc[k * 4 + 3] = __int_as_float(__builtin_amdgcn_readlane(__float_as_int(o3), k));
    }
}

// Evolve NS states through the full circuit (both layers + entangler diags).
__device__ __forceinline__ void evolve(float (&v0r)[NS], float (&v0i)[NS],
                                       float (&v1r)[NS], float (&v1i)[NS],
                                       const float (&gc)[56], int lane) {
#define GAPPLY(gi)                                                        \
    {                                                                     \
        float ur = gc[(gi)*4 + 0], ui = gc[(gi)*4 + 1];                   \
        float vr = gc[(gi)*4 + 2], vi = gc[(gi)*4 + 3];                   \
        _Pragma("unroll") for (int s = 0; s < NS; ++s) {                  \
            float n0r = ur * v0r[s] - ui * v0i[s] - vr * v1r[s] - vi * v1i[s]; \
            float n0i = ur * v0i[s] + ui * v0r[s] + vi * v1r[s] - vr * v1i[s]; \
            float n1r = vr * v0r[s] - vi * v0i[s] + ur * v1r[s] + ui * v1i[s]; \
            float n1i = vr * v0i[s] + vi * v0r[s] + ur * v1i[s] - ui * v1r[s]; \
            v0r[s] = n0r; v0i[s] = n0i; v1r[s] = n1r; v1i[s] = n1i;       \
        }                                                                 \
    }
#define RP32()                                                            \
    {                                                                     \
        _Pragma("unroll") for (int s = 0; s < NS; ++s) {                  \
            asm("v_permlane32_swap_b32 %0, %1" : "+v"(v0r[s]), "+v"(v1r[s])); \
            asm("v_permlane32_swap_b32 %0, %1" : "+v"(v0i[s]), "+v"(v1i[s])); \
        }                                                                 \
    }
#define RP16()                                                            \
    {                                                                     \
        _Pragma("unroll") for (int s = 0; s < NS; ++s) {                  \
            asm("v_permlane16_swap_b32 %0, %1" : "+v"(v0r[s]), "+v"(v1r[s])); \
            asm("v_permlane16_swap_b32 %0, %1" : "+v"(v0i[s]), "+v"(v1i[s])); \
        }                                                                 \
    }
#define RPB(m)                                                            \
    {                                                                     \
        bool hi = (lane & (m)) != 0;                                      \
        int ad = (lane ^ (m)) << 2;                                       \
        _Pragma("unroll") for (int s = 0; s < NS; ++s) {                  \
            float sr = hi ? v0r[s] : v1r[s];                              \
            float si = hi ? v0i[s] : v1i[s];                              \
            float rr = bperm(ad, sr);                                     \
            float ri = bperm(ad, si);                                     \
            v0r[s] = hi ? rr : v0r[s];                                    \
            v0i[s] = hi ? ri : v0i[s];                                    \
            v1r[s] = hi ? v1r[s] : rr;                                    \
            v1i[s] = hi ? v1i[s] : ri;                                    \
        }                                                                 \
    }
#define RPD(m, CTRL)                                                      \
    {                                                                     \
        bool hi = (lane & (m)) != 0;                                      \
        _Pragma("unroll") for (int s = 0; s < NS; ++s) {                  \
            float t0r = fdpp<CTRL>(v0r[s]), t0i = fdpp<CTRL>(v0i[s]);     \
            float t1r = fdpp<CTRL>(v1r[s]), t1i = fdpp<CTRL>(v1i[s]);     \
            v0r[s] = hi ? t1r : v0r[s];                                   \
            v0i[s] = hi ? t1i : v0i[s];                                   \
            v1r[s] = hi ? v1r[s] : t0r;                                   \
            v1i[s] = hi ? v1i[s] : t0i;                                   \
        }                                                                 \
    }
    {
        float ur = gc[0], ui = gc[1], vr = gc[2], vi = gc[3];
#pragma unroll
        for (int s = 0; s < NS; ++s) {
            float xx = v0r[s];
            v0r[s] = ur * xx; v0i[s] = ui * xx;
            v1r[s] = vr * xx; v1i[s] = vi * xx;
        }
    }
    RP32();
    {
        float ur = gc[4], ui = gc[5], vr = gc[6], vi = gc[7];
#pragma unroll
        for (int s = 0; s < NS; ++s) {
            float x0r = v0r[s], x0i = v0i[s];
            v0r[s] = ur * x0r - ui * x0i; v0i[s] = ur * x0i + ui * x0r;
            v1r[s] = vr * x0r - vi * x0i; v1i[s] = vr * x0i + vi * x0r;
        }
    }
    RP16();       GAPPLY(2);
    RPB(8);       GAPPLY(3);
    RPB(4);       GAPPLY(4);
    RPD(2, 0x4E); GAPPLY(5);
    RPD(1, 0xB1); GAPPLY(6);

    int kc = __popc(lane);
    float s0 = ((kc >> 1) & 1) ? -1.f : 1.f;
    float s1 = (((kc + 1) >> 1) & 1) ? -1.f : 1.f;
#pragma unroll
    for (int s = 0; s < NS; ++s) {
        v0r[s] *= s0; v0i[s] *= s0; v1r[s] *= s1; v1i[s] *= s1;
    }

    RP32();       GAPPLY(7);
    RP16();       GAPPLY(8);
    RPB(8);       GAPPLY(9);
    RPB(4);       GAPPLY(10);
    RPD(2, 0x4E); GAPPLY(11);
    RPD(1, 0xB1); GAPPLY(12);
    RP32();       GAPPLY(13);
#pragma unroll
    for (int s = 0; s < NS; ++s) {
        v0r[s] *= s0; v0i[s] *= s0; v1r[s] *= s1; v1i[s] *= s1;
    }
#undef GAPPLY
#undef RP32
#undef RP16
#undef RPB
#undef RPD
}

__device__ __forceinline__ void measure(float (&v0r)[NS], float (&v0i)[NS],
                                        float (&v1r)[NS], float (&v1i)[NS],
                                        int lane, float (&e)[NS]) {
#pragma unroll
    for (int s = 0; s < NS; ++s) {
        float t = v0r[s] * v0r[s] + v0i[s] * v0i[s] + v1r[s] * v1r[s] + v1i[s] * v1i[s];
        e[s] = (lane & 16) ? -t : t;
        e[s] = dpp_reduce(e[s]);
    }
}

// triangular pair offset: off(k) = 31k - k(k-1)/2 (row k holds l=k+1..31)
__device__ __forceinline__ int pair_off(int k) { return 31 * k - (k * (k - 1)) / 2; }

// ---------------- kernel 1: basis evolutions -> f values --------------------
__global__ __launch_bounds__(512) void prep_k(const float* __restrict__ thetas,
                                              float* __restrict__ fbuf) {
    int lane = threadIdx.x & 63;
    int iw = threadIdx.x >> 6;
    int oc = __builtin_amdgcn_readfirstlane(blockIdx.x / 17);
    int chunk = blockIdx.x % 17;

    float gc[56];
    make_gates(thetas, oc, lane, gc);

    float v0r[NS], v0i[NS], v1r[NS], v1i[NS];
    int idxs[NS];
#pragma unroll
    for (int s = 0; s < NS; ++s) {
        int idx = chunk * 32 + iw * 4 + s;
        if (idx > 527) idx = 527;
        idxs[s] = idx;
        int k, l;
        if (idx < 32) {
            k = idx; l = idx;
        } else {
            int p = idx - 32;
            // closed form: largest k with off(k) <= p ; discriminant is exact
            k = (int)((63.0f - sqrtf(3969.0f - 8.0f * (float)p)) * 0.5f);
            if (k > 0 && pair_off(k) > p) --k;
            if (pair_off(k + 1) <= p) ++k;
            l = k + 1 + (p - pair_off(k));
        }
        v0r[s] = (lane == k || lane == l) ? 1.f : 0.f;
        v0i[s] = 0.f; v1r[s] = 0.f; v1i[s] = 0.f;
    }

    evolve(v0r, v0i, v1r, v1i, gc, lane);
    float e[NS];
    measure(v0r, v0i, v1r, v1i, lane, e);
    if (lane == 63) {
#pragma unroll
        for (int s = 0; s < NS; ++s) fbuf[oc * 544 + idxs[s]] = e[s];
    }
}

// ---------------- kernel 2: triangular U assembly ---------------------------
// U layout per oc (stride 544): t = off(k) + ... stored row-major triangular:
// row k occupies [trioff(k), trioff(k)+ (32-k)) with trioff(k)=32k-k(k-1)/2,
// entry l>=k. U_kk = f_k ; U_kl = f_pair - f_k - f_l  (= 2 A_kl).
__global__ void asm_k(const float* __restrict__ fbuf, float* __restrict__ U) {
    int e = blockIdx.x * 512 + threadIdx.x;  // 9 blocks x 512 >= 8*528
    if (e >= 8 * 528) return;
    int oc = e / 528, t = e - oc * 528;
    // decode triangular row: trioff(k) = 32k - k(k-1)/2
    int k = (int)((65.0f - sqrtf(4225.0f - 8.0f * (float)t)) * 0.5f);
    int tk = 32 * k - (k * (k - 1)) / 2;
    if (k > 0 && tk > t) { --k; tk = 32 * k - (k * (k - 1)) / 2; }
    if (32 * (k + 1) - (k * (k + 1)) / 2 <= t) { tk = 32 * (k + 1) - (k * (k + 1)) / 2; ++k; }
    int l = k + (t - tk);
    const float* fo = fbuf + oc * 544;
    float v;
    if (k == l) {
        v = fo[k];
    } else {
        v = fo[32 + pair_off(k) + (l - k - 1)] - fo[k] - fo[l];
    }
    U[oc * 544 + t] = v;
}

// ---------------- kernel 3: triangular quadratic form -----------------------
__global__ __launch_bounds__(512) void quad_k(const float* __restrict__ x,
                                              const float* __restrict__ U,
                                              float* __restrict__ out) {
    int lane = threadIdx.x & 63;
    int oc = __builtin_amdgcn_readfirstlane((int)(threadIdx.x >> 6));
    int row = blockIdx.x * 64 + lane;
    bool valid = row < N_ROWS;
    int rc = valid ? row : (N_ROWS - 1);
    int b = rc / L_OUT;
    int l = rc - b * L_OUT;

    const float* xb = x + (b * 4) * 2048 + l;
    float w[32];
#pragma unroll
    for (int c = 0; c < 4; ++c)
#pragma unroll
        for (int k = 0; k < 8; ++k) w[c * 8 + k] = xb[c * 2048 + k];

    float n2 = 0.f;
#pragma unroll
    for (int i = 0; i < 32; ++i) n2 = fmaf(w[i], w[i], n2);

    const float* Uo = U + oc * 544;  // wave-uniform, read strictly sequentially
    float acc0 = 0.f, acc1 = 0.f;
#pragma unroll
    for (int k = 0; k < 32; ++k) {
        const float* Ur = Uo + (32 * k - (k * (k - 1)) / 2) - k;  // index by l
        float t0 = 0.f, t1 = 0.f;
#pragma unroll
        for (int j = k; j < 32; j += 2) t0 = fmaf(Ur[j], w[j], t0);
#pragma unroll
        for (int j = k + 1; j < 32; j += 2) t1 = fmaf(Ur[j], w[j], t1);
        if (k & 1) acc1 = fmaf(w[k], t0 + t1, acc1);
        else       acc0 = fmaf(w[k], t0 + t1, acc0);
    }
    if (valid)
        out[(b * 8 + oc) * L_OUT + l] = (acc0 + acc1) * __builtin_amdgcn_rcpf(n2);
}

// ---------------- fallback: direct evolution (R4-style) ---------------------
__global__ __launch_bounds__(512) void direct_k(const float* __restrict__ x,
                                                const float* __restrict__ thetas,
                                                float* __restrict__ out) {
    int lane = threadIdx.x & 63;
    int oc = __builtin_amdgcn_readfirstlane((int)(threadIdx.x >> 6));
    float gc[56];
    make_gates(thetas, oc, lane, gc);

    int row0 = blockIdx.x * NS;
    int bidx[NS], lidx[NS];
    float v0r[NS], v0i[NS], v1r[NS], v1i[NS], acc[NS];
#pragma unroll
    for (int s = 0; s < NS; ++s) {
        int row = row0 + s;
        int b = row / L_OUT;
        bidx[s] = b;
        lidx[s] = row - b * L_OUT;
        float t = 0.f;
        if (lane < 32) {
            int c = lane >> 3, k = lane & 7;
            t = x[(b * 4 + c) * 2048 + lidx[s] + k];
        }
        acc[s] = t * t;
        v0r[s] = t; v0i[s] = 0.f; v1r[s] = 0.f; v1i[s] = 0.f;
    }
    evolve(v0r, v0i, v1r, v1i, gc, lane);
    float e[NS];
    measure(v0r, v0i, v1r, v1i, lane, e);
#pragma unroll
    for (int s = 0; s < NS; ++s) acc[s] = dpp_reduce(acc[s]);
    if (lane == 63) {
#pragma unroll
        for (int s = 0; s < NS; ++s)
            out[(bidx[s] * 8 + oc) * L_OUT + lidx[s]] =
                e[s] * __builtin_amdgcn_rcpf(acc[s]);
    }
}

extern "C" void kernel_launch(void* const* d_in, const int* in_sizes, int n_in,
                              void* d_out, int out_size, void* d_ws, size_t ws_size,
                              hipStream_t stream) {
    const float* x = (const float*)d_in[0];
    const float* thetas = (const float*)d_in[1];
    float* out = (float*)d_out;

    // ws: f values 8*544 floats, then U 8*544 floats.
    if (ws_size >= (8 * 544 * 2) * sizeof(float)) {
        float* fbuf = (float*)d_ws;
        float* U = fbuf + 8 * 544;
        prep_k<<<136, 512, 0, stream>>>(thetas, fbuf);
        asm_k<<<9, 512, 0, stream>>>(fbuf, U);
        quad_k<<<(N_ROWS + 63) / 64, 512, 0, stream>>>(x, U, out);
    } else {
        direct_k<<<N_ROWS / NS, 512, 0, stream>>>(x, thetas, out);
    }
}

// Round 7
// 72.332 us; speedup vs baseline: 2.8171x; 1.0270x over previous
//
#include <hip/hip_runtime.h>

// MoreParamDenseQConv1D — algebraic reduction, 2-kernel pipeline.
// out(r,oc) = w^T A_oc w / (w^T w), A_oc = Re(W[:,:32]^H diag(z0) W[:,:32]).
// With f_k = e_k^T A e_k and f_kl = (e_k+e_l)^T A (e_k+e_l):
//   w^T A w = sum_{k<l} f_kl w_k w_l + sum_k f_k w_k (2 w_k - S),  S = sum w.
// Pipeline:
//   1) prep_k : evolve 528 basis inputs per oc (32 singles, 496 pairs) with
//      the verified wave-level circuit machinery -> f values in ws.
//   2) quad_k : one thread per (row,oc); 32 window floats in VGPRs; row-
//      factored pair sum (496 FMA) + diagonal correction; divide by ||w||^2.
// No asm kernel: polarization is folded into quad's correction term.

#define L_OUT 2041
#define N_ROWS (16 * L_OUT)   // 32656
#define NS 4

// ---------------- wave-level circuit machinery (verified R1-R6) -------------

__device__ __forceinline__ float bperm(int addr, float v) {
    return __int_as_float(__builtin_amdgcn_ds_bpermute(addr, __float_as_int(v)));
}

template <int CTRL>
__device__ __forceinline__ float fdpp(float v) {
    return __int_as_float(
        __builtin_amdgcn_mov_dpp(__float_as_int(v), CTRL, 0xf, 0xf, true));
}

// Full-wave sum; total lands in lane 63.
__device__ __forceinline__ float dpp_reduce(float v) {
    v += fdpp<0x111>(v);  // row_shr:1
    v += fdpp<0x112>(v);  // row_shr:2
    v += fdpp<0x114>(v);  // row_shr:4
    v += fdpp<0x118>(v);  // row_shr:8
    v += fdpp<0x142>(v);  // row_bcast:15
    v += fdpp<0x143>(v);  // row_bcast:31
    return v;
}

__device__ __forceinline__ void make_gates(const float* __restrict__ thetas,
                                           int oc, int lane, float* gc) {
    float o0, o1, o2, o3;
    {
        int g = lane < 14 ? lane : 0;
        int ti = (oc * 14 + g) * 3;
        float a = thetas[ti + 0], b = thetas[ti + 1], gm = thetas[ti + 2];
        float sb = sinf(b * 0.5f), cb = cosf(b * 0.5f);
        float sp, cp, sm, cm;
        sincosf((a + gm) * 0.5f, &sp, &cp);
        sincosf((a - gm) * 0.5f, &sm, &cm);
        o0 = cp * cb;
        o1 = -sp * cb;
        o2 = cm * sb;
        o3 = sm * sb;
    }
#pragma unroll
    for (int k = 0; k < 14; ++k) {
        gc[k * 4 + 0] = __int_as_float(__builtin_amdgcn_readlane(__float_as_int(o0), k));
        gc[k * 4 + 1] = __int_as_float(__builtin_amdgcn_readlane(__float_as_int(o1), k));
        gc[k * 4 + 2] = __int_as_float(__builtin_amdgcn_readlane(__float_as_int(o2), k));
        gc[k * 4 + 3] = __int_as_float(__builtin_amdgcn_readlane(__float_as_int(o3), k));
    }
}

// Evolve NS states through the full circuit (both layers + entangler diags).
__device__ __forceinline__ void evolve(float (&v0r)[NS], float (&v0i)[NS],
                                       float (&v1r)[NS], float (&v1i)[NS],
                                       const float (&gc)[56], int lane) {
#define GAPPLY(gi)                                                        \
    {                                                                     \
        float ur = gc[(gi)*4 + 0], ui = gc[(gi)*4 + 1];                   \
        float vr = gc[(gi)*4 + 2], vi = gc[(gi)*4 + 3];                   \
        _Pragma("unroll") for (int s = 0; s < NS; ++s) {                  \
            float n0r = ur * v0r[s] - ui * v0i[s] - vr * v1r[s] - vi * v1i[s]; \
            float n0i = ur * v0i[s] + ui * v0r[s] + vi * v1r[s] - vr * v1i[s]; \
            float n1r = vr * v0r[s] - vi * v0i[s] + ur * v1r[s] + ui * v1i[s]; \
            float n1i = vr * v0i[s] + vi * v0r[s] + ur * v1i[s] - ui * v1r[s]; \
            v0r[s] = n0r; v0i[s] = n0i; v1r[s] = n1r; v1i[s] = n1i;       \
        }                                                                 \
    }
#define RP32()                                                            \
    {                                                                     \
        _Pragma("unroll") for (int s = 0; s < NS; ++s) {                  \
            asm("v_permlane32_swap_b32 %0, %1" : "+v"(v0r[s]), "+v"(v1r[s])); \
            asm("v_permlane32_swap_b32 %0, %1" : "+v"(v0i[s]), "+v"(v1i[s])); \
        }                                                                 \
    }
#define RP16()                                                            \
    {                                                                     \
        _Pragma("unroll") for (int s = 0; s < NS; ++s) {                  \
            asm("v_permlane16_swap_b32 %0, %1" : "+v"(v0r[s]), "+v"(v1r[s])); \
            asm("v_permlane16_swap_b32 %0, %1" : "+v"(v0i[s]), "+v"(v1i[s])); \
        }                                                                 \
    }
#define RPB(m)                                                            \
    {                                                                     \
        bool hi = (lane & (m)) != 0;                                      \
        int ad = (lane ^ (m)) << 2;                                       \
        _Pragma("unroll") for (int s = 0; s < NS; ++s) {                  \
            float sr = hi ? v0r[s] : v1r[s];                              \
            float si = hi ? v0i[s] : v1i[s];                              \
            float rr = bperm(ad, sr);                                     \
            float ri = bperm(ad, si);                                     \
            v0r[s] = hi ? rr : v0r[s];                                    \
            v0i[s] = hi ? ri : v0i[s];                                    \
            v1r[s] = hi ? v1r[s] : rr;                                    \
            v1i[s] = hi ? v1i[s] : ri;                                    \
        }                                                                 \
    }
#define RPD(m, CTRL)                                                      \
    {                                                                     \
        bool hi = (lane & (m)) != 0;                                      \
        _Pragma("unroll") for (int s = 0; s < NS; ++s) {                  \
            float t0r = fdpp<CTRL>(v0r[s]), t0i = fdpp<CTRL>(v0i[s]);     \
            float t1r = fdpp<CTRL>(v1r[s]), t1i = fdpp<CTRL>(v1i[s]);     \
            v0r[s] = hi ? t1r : v0r[s];                                   \
            v0i[s] = hi ? t1i : v0i[s];                                   \
            v1r[s] = hi ? v1r[s] : t0r;                                   \
            v1i[s] = hi ? v1i[s] : t0i;                                   \
        }                                                                 \
    }
    {
        float ur = gc[0], ui = gc[1], vr = gc[2], vi = gc[3];
#pragma unroll
        for (int s = 0; s < NS; ++s) {
            float xx = v0r[s];
            v0r[s] = ur * xx; v0i[s] = ui * xx;
            v1r[s] = vr * xx; v1i[s] = vi * xx;
        }
    }
    RP32();
    {
        float ur = gc[4], ui = gc[5], vr = gc[6], vi = gc[7];
#pragma unroll
        for (int s = 0; s < NS; ++s) {
            float x0r = v0r[s], x0i = v0i[s];
            v0r[s] = ur * x0r - ui * x0i; v0i[s] = ur * x0i + ui * x0r;
            v1r[s] = vr * x0r - vi * x0i; v1i[s] = vr * x0i + vi * x0r;
        }
    }
    RP16();       GAPPLY(2);
    RPB(8);       GAPPLY(3);
    RPB(4);       GAPPLY(4);
    RPD(2, 0x4E); GAPPLY(5);
    RPD(1, 0xB1); GAPPLY(6);

    int kc = __popc(lane);
    float s0 = ((kc >> 1) & 1) ? -1.f : 1.f;
    float s1 = (((kc + 1) >> 1) & 1) ? -1.f : 1.f;
#pragma unroll
    for (int s = 0; s < NS; ++s) {
        v0r[s] *= s0; v0i[s] *= s0; v1r[s] *= s1; v1i[s] *= s1;
    }

    RP32();       GAPPLY(7);
    RP16();       GAPPLY(8);
    RPB(8);       GAPPLY(9);
    RPB(4);       GAPPLY(10);
    RPD(2, 0x4E); GAPPLY(11);
    RPD(1, 0xB1); GAPPLY(12);
    RP32();       GAPPLY(13);
#pragma unroll
    for (int s = 0; s < NS; ++s) {
        v0r[s] *= s0; v0i[s] *= s0; v1r[s] *= s1; v1i[s] *= s1;
    }
#undef GAPPLY
#undef RP32
#undef RP16
#undef RPB
#undef RPD
}

__device__ __forceinline__ void measure(float (&v0r)[NS], float (&v0i)[NS],
                                        float (&v1r)[NS], float (&v1i)[NS],
                                        int lane, float (&e)[NS]) {
#pragma unroll
    for (int s = 0; s < NS; ++s) {
        float t = v0r[s] * v0r[s] + v0i[s] * v0i[s] + v1r[s] * v1r[s] + v1i[s] * v1i[s];
        e[s] = (lane & 16) ? -t : t;
        e[s] = dpp_reduce(e[s]);
    }
}

// pair offset: off(k) = 31k - k(k-1)/2 (row k holds l=k+1..31)
__device__ __forceinline__ int pair_off(int k) { return 31 * k - (k * (k - 1)) / 2; }

// ---------------- kernel 1: basis evolutions -> f values --------------------
// fbuf layout per oc (stride 544): [0..31] singles f_k ; [32+off(k)+l-k-1] pairs.
__global__ __launch_bounds__(512) void prep_k(const float* __restrict__ thetas,
                                              float* __restrict__ fbuf) {
    int lane = threadIdx.x & 63;
    int iw = threadIdx.x >> 6;
    int oc = __builtin_amdgcn_readfirstlane(blockIdx.x / 17);
    int chunk = blockIdx.x % 17;

    float gc[56];
    make_gates(thetas, oc, lane, gc);

    float v0r[NS], v0i[NS], v1r[NS], v1i[NS];
    int idxs[NS];
#pragma unroll
    for (int s = 0; s < NS; ++s) {
        int idx = chunk * 32 + iw * 4 + s;
        if (idx > 527) idx = 527;
        idxs[s] = idx;
        int k, l;
        if (idx < 32) {
            k = idx; l = idx;
        } else {
            int p = idx - 32;
            // closed form: largest k with off(k) <= p ; discriminant is exact
            k = (int)((63.0f - sqrtf(3969.0f - 8.0f * (float)p)) * 0.5f);
            if (k > 0 && pair_off(k) > p) --k;
            if (pair_off(k + 1) <= p) ++k;
            l = k + 1 + (p - pair_off(k));
        }
        v0r[s] = (lane == k || lane == l) ? 1.f : 0.f;
        v0i[s] = 0.f; v1r[s] = 0.f; v1i[s] = 0.f;
    }

    evolve(v0r, v0i, v1r, v1i, gc, lane);
    float e[NS];
    measure(v0r, v0i, v1r, v1i, lane, e);
    if (lane == 63) {
#pragma unroll
        for (int s = 0; s < NS; ++s) fbuf[oc * 544 + idxs[s]] = e[s];
    }
}

// ---------------- kernel 2: quadratic form directly from f ------------------
// out*n2 = sum_k w_k * [ sum_{l>k} f_kl w_l + f_k*(2 w_k - S) ]
__global__ __launch_bounds__(512) void quad_k(const float* __restrict__ x,
                                              const float* __restrict__ F,
                                              float* __restrict__ out) {
    int lane = threadIdx.x & 63;
    int oc = __builtin_amdgcn_readfirstlane((int)(threadIdx.x >> 6));
    int row = blockIdx.x * 64 + lane;
    bool valid = row < N_ROWS;
    int rc = valid ? row : (N_ROWS - 1);
    int b = rc / L_OUT;
    int l = rc - b * L_OUT;

    const float* xb = x + (b * 4) * 2048 + l;
    float w[32];
#pragma unroll
    for (int c = 0; c < 4; ++c)
#pragma unroll
        for (int k = 0; k < 8; ++k) w[c * 8 + k] = xb[c * 2048 + k];

    float n2 = 0.f, S = 0.f;
#pragma unroll
    for (int i = 0; i < 32; ++i) {
        n2 = fmaf(w[i], w[i], n2);
        S += w[i];
    }

    const float* fo = F + oc * 544;  // wave-uniform, read sequentially
    float acc0 = 0.f, acc1 = 0.f;
#pragma unroll
    for (int k = 0; k < 32; ++k) {
        // pairs for row k live at fo[32 + pair_off(k) + (l-k-1)]
        const float* fr = fo + 32 + (31 * k - (k * (k - 1)) / 2) - k - 1;
        float t0 = 0.f, t1 = 0.f;
#pragma unroll
        for (int j = k + 1; j < 32; j += 2) t0 = fmaf(fr[j], w[j], t0);
#pragma unroll
        for (int j = k + 2; j < 32; j += 2) t1 = fmaf(fr[j], w[j], t1);
        float t = fmaf(fo[k], fmaf(2.f, w[k], -S), t0 + t1);
        if (k & 1) acc1 = fmaf(w[k], t, acc1);
        else       acc0 = fmaf(w[k], t, acc0);
    }
    if (valid)
        out[(b * 8 + oc) * L_OUT + l] = (acc0 + acc1) * __builtin_amdgcn_rcpf(n2);
}

// ---------------- fallback: direct evolution (R4-style) ---------------------
__global__ __launch_bounds__(512) void direct_k(const float* __restrict__ x,
                                                const float* __restrict__ thetas,
                                                float* __restrict__ out) {
    int lane = threadIdx.x & 63;
    int oc = __builtin_amdgcn_readfirstlane((int)(threadIdx.x >> 6));
    float gc[56];
    make_gates(thetas, oc, lane, gc);

    int row0 = blockIdx.x * NS;
    int bidx[NS], lidx[NS];
    float v0r[NS], v0i[NS], v1r[NS], v1i[NS], acc[NS];
#pragma unroll
    for (int s = 0; s < NS; ++s) {
        int row = row0 + s;
        int b = row / L_OUT;
        bidx[s] = b;
        lidx[s] = row - b * L_OUT;
        float t = 0.f;
        if (lane < 32) {
            int c = lane >> 3, k = lane & 7;
            t = x[(b * 4 + c) * 2048 + lidx[s] + k];
        }
        acc[s] = t * t;
        v0r[s] = t; v0i[s] = 0.f; v1r[s] = 0.f; v1i[s] = 0.f;
    }
    evolve(v0r, v0i, v1r, v1i, gc, lane);
    float e[NS];
    measure(v0r, v0i, v1r, v1i, lane, e);
#pragma unroll
    for (int s = 0; s < NS; ++s) acc[s] = dpp_reduce(acc[s]);
    if (lane == 63) {
#pragma unroll
        for (int s = 0; s < NS; ++s)
            out[(bidx[s] * 8 + oc) * L_OUT + lidx[s]] =
                e[s] * __builtin_amdgcn_rcpf(acc[s]);
    }
}

extern "C" void kernel_launch(void* const* d_in, const int* in_sizes, int n_in,
                              void* d_out, int out_size, void* d_ws, size_t ws_size,
                              hipStream_t stream) {
    const float* x = (const float*)d_in[0];
    const float* thetas = (const float*)d_in[1];
    float* out = (float*)d_out;

    if (ws_size >= (8 * 544) * sizeof(float)) {
        float* fbuf = (float*)d_ws;
        prep_k<<<136, 512, 0, stream>>>(thetas, fbuf);
        quad_k<<<(N_ROWS + 63) / 64, 512, 0, stream>>>(x, fbuf, out);
    } else {
        direct_k<<<N_ROWS / NS, 512, 0, stream>>>(x, thetas, out);
    }
}